// Round 2
// baseline (215.929 us; speedup 1.0000x reference)
//
#include <hip/hip_runtime.h>
#include <cstdint>

typedef _Float16 half8 __attribute__((ext_vector_type(8)));
typedef __fp16 fp16x2 __attribute__((ext_vector_type(2)));
typedef float f32x4 __attribute__((ext_vector_type(4)));

// ws layout (halfs), per head 2048*64 = 131072 per tensor:
//  Kt: [head] fragment-order: frag(st=s/16, ks) at (st*2+ks)*512 + lane*8,
//      lane(q,l15) 8 halfs = K[16st+l15][32ks+8q+j]           (A-frag for S^T)
//  Vt: [head] sigma-fragment-order: frag(sc=s/32, ct) at (sc*4+ct)*512 + lane*8,
//      lane(q,l15) 8 halfs j = V[16ct+l15][32sc+4q+(j&3)+16(j>>2)]  (A-frag for O)
#define HSTRIDE 131072
#define KOFF    ((size_t)64 * HSTRIDE)
#define VOFF    ((size_t)128 * HSTRIDE)

__device__ __forceinline__ float fast_exp2(float x) {
    return __builtin_amdgcn_exp2f(x);
}

__device__ __forceinline__ uint32_t pkrtz(float a, float b) {
    fp16x2 h = __builtin_amdgcn_cvt_pkrtz(a, b);
    return __builtin_bit_cast(uint32_t, h);
}

__device__ __forceinline__ void load_lds16(const _Float16* g, _Float16* l) {
    auto* g1 = reinterpret_cast<const __attribute__((address_space(1))) uint32_t*>(
        reinterpret_cast<uintptr_t>(g));
    auto* l3 = reinterpret_cast<__attribute__((address_space(3))) uint32_t*>(
        reinterpret_cast<uintptr_t>(l));
    __builtin_amdgcn_global_load_lds(g1, l3, 16, 0, 0);
}

// ---------------- prep: K transpose + V sigma-pack (unchanged) ----------------
__global__ __launch_bounds__(256) void prep_kernel(const float* __restrict__ qkv,
                                                   _Float16* __restrict__ ws)
{
    __shared__ float Lf[64 * 67];        // 16.75 KB (K branch only)

    const int tid  = threadIdx.x;
    const int lane = tid & 63;
    const int wave = tid >> 6;
    const int bid  = blockIdx.x;

    if (bid < 2048) {
        // ---- K ----
        const int head  = (bid >> 5) & 63;
        const int chunk = bid & 31;          // 64-wide s chunk
        const int b4 = head >> 4, h = head & 15;
        const float* src = qkv + (((size_t)(b4 * 3072 + h * 192 + 64)) << 11)
                         + chunk * 64;

#pragma unroll
        for (int k = 0; k < 4; ++k) {
            int idx = k * 256 + tid;
            int c = idx >> 4;
            int t4 = (idx & 15) << 2;
            float4 f = *(const float4*)&src[(((size_t)c) << 11) + t4];
            float* d = &Lf[c * 67 + t4];
            d[0] = f.x; d[1] = f.y; d[2] = f.z; d[3] = f.w;
        }
        __syncthreads();

        const int q = lane >> 4, l15 = lane & 15;
        const int scol = wave * 16 + l15;    // s within chunk
#pragma unroll
        for (int k = 0; k < 2; ++k) {
            uint32_t d[4];
#pragma unroll
            for (int j = 0; j < 4; ++j) {
                float a = Lf[(32 * k + 8 * q + 2 * j) * 67 + scol];
                float b = Lf[(32 * k + 8 * q + 2 * j + 1) * 67 + scol];
                d[j] = pkrtz(a, b);
            }
            size_t off = KOFF + (size_t)head * HSTRIDE
                       + (size_t)((((chunk * 4 + wave) * 2 + k) * 512) + lane * 8);
            *(uint4*)&ws[off] = make_uint4(d[0], d[1], d[2], d[3]);
        }
    } else {
        // ---- V ----
        const int vb = bid - 2048;
        const int head = vb >> 5, chunk = vb & 31;   // 64-s chunk
        const int b4 = head >> 4, h = head & 15;
        const float* src = qkv + (((size_t)(b4 * 3072 + h * 192 + 128)) << 11) + chunk * 64;
        const int q = lane >> 4, cl = lane & 15;
        const int c = wave * 16 + cl;
#pragma unroll
        for (int k = 0; k < 2; ++k) {
            const float* p = &src[((size_t)c << 11) + k * 32 + q * 4];
            float4 f0 = *(const float4*)&p[0];      // s = 4q..4q+3   (j=0..3)
            float4 f1 = *(const float4*)&p[16];     // s = 16+4q..+3  (j=4..7)
            size_t off = VOFF + (size_t)head * HSTRIDE
                       + (size_t)(((chunk * 2 + k) * 4 + wave) * 512 + lane * 8);
            *(uint4*)&ws[off] = make_uint4(pkrtz(f0.x, f0.y), pkrtz(f0.z, f0.w),
                                           pkrtz(f1.x, f1.y), pkrtz(f1.z, f1.w));
        }
    }
}

// ---------------- flash attention: exp hidden under O-MFMAs ----------------
// Round-10 change vs round-9: round-9's counters (MfmaUtil 40 + VALUBusy 37,
// phases SUM not MAX) showed the exp block still serializes after all 72
// MFMAs: body was [O-mfma][S-mfma][exps]. Now the body is
//   [ds_read][32 S(it+1) MFMAs -> Sa/Sb live][4x: 8 O(it)+2 Lacc MFMA || 16 exp+8 pack]
// so the whole VALU load (exps of tile it+1) is independent of, and source-
// interleaved with, the O MFMAs of tile it (which consume the PREVIOUS pf).
// Intra-wave overlap -> robust to the two co-resident blocks running in-phase.
// pf ping-pongs between two statically-named register sets (pfA/pfB, rule:
// runtime-indexed arrays spill to scratch); vf reads moved inside ct-groups to
// cap peak VGPR (~230 <= 256; occupancy is grid-capped at 2 waves/SIMD so
// VGPRs are free). Sync structure identical to round-9.
__launch_bounds__(256, 2)
__global__ void attn_kernel(const float* __restrict__ qkv,
                            const _Float16* __restrict__ ws, float* __restrict__ out)
{
    __shared__ __align__(16) _Float16 sK[3][4096];   // 3 x 8 KB, fragment-linear
    __shared__ __align__(16) _Float16 sV[3][4096];   // 3 x 8 KB, fragment-linear

    const int tid  = threadIdx.x;
    const int lane = tid & 63;
    const int wave = tid >> 6;
    const int l15  = lane & 15;
    const int quad = lane >> 4;

    const int bid  = blockIdx.x;
    const int head = bid & 63;
    const int tblk = bid >> 6;
    const int T0   = tblk * 256;
    const int b4   = head >> 4;
    const int h    = head & 15;

    const _Float16* Kt = ws + KOFF + (size_t)head * HSTRIDE;
    const _Float16* Vt = ws + VOFF + (size_t)head * HSTRIDE;
    const float*    Qg = qkv + ((size_t)(b4 * 3072 + h * 192) << 11);
    const float kQ = 0.125f * 1.44269504088896340736f;  // scale^2 * log2(e)

    f32x4 Oacc[4][4];
#pragma unroll
    for (int ct = 0; ct < 4; ++ct)
#pragma unroll
        for (int nt = 0; nt < 4; ++nt) Oacc[ct][nt] = (f32x4)0.f;
    f32x4 Lacc[4];
#pragma unroll
    for (int nt = 0; nt < 4; ++nt) Lacc[nt] = (f32x4)0.f;
    const f32x4 fz = (f32x4)0.f;

    half8 ones;
#pragma unroll
    for (int j = 0; j < 8; ++j) ones[j] = (_Float16)1.0f;

    const int lb = lane * 8;

    auto stage = [&](int buf, int tile) {
        const _Float16* kg = Kt + (size_t)tile * 4096 + wave * 1024 + lane * 8;
        const _Float16* vg = Vt + (size_t)tile * 4096 + wave * 1024 + lane * 8;
        load_lds16(kg,       &sK[buf][wave * 1024]);
        load_lds16(kg + 512, &sK[buf][wave * 1024 + 512]);
        load_lds16(vg,       &sV[buf][wave * 1024]);
        load_lds16(vg + 512, &sV[buf][wave * 1024 + 512]);
    };

    stage(0, 0);   // tiles 0 and 1 in flight before/under the Q gather
    stage(1, 1);

    // Q B-frags: B[k=c=32ks+8q+j][n=t=16nt+l15], direct fp32 gather + scale + pack.
    half8 qb[4][2];
#pragma unroll
    for (int nt = 0; nt < 4; ++nt) {
        const int t = T0 + wave * 64 + nt * 16 + l15;
#pragma unroll
        for (int ks = 0; ks < 2; ++ks) {
            float f[8];
#pragma unroll
            for (int j = 0; j < 8; ++j)
                f[j] = Qg[((size_t)(ks * 32 + quad * 8 + j) << 11) + t];
            uint4 u = make_uint4(pkrtz(f[0] * kQ, f[1] * kQ), pkrtz(f[2] * kQ, f[3] * kQ),
                                 pkrtz(f[4] * kQ, f[5] * kQ), pkrtz(f[6] * kQ, f[7] * kQ));
            qb[nt][ks] = __builtin_bit_cast(half8, u);
        }
    }

    half8 pfA[2][4], pfB[2][4];   // P^T B-frags, ping-pong pipeline state
    int bV = 0;                   // buffer holding tile `it` (tile t -> buf t%3)

    // ---- loop body: O(it) with PFo, S(it+1) -> exps -> PFn ----
    auto body = [&](int it, half8 (&PFo)[2][4], half8 (&PFn)[2][4]) {
        __builtin_amdgcn_s_waitcnt(0);   // own prefetch (tile it+1) resident
        __syncthreads();                 // all waves: tile it+1 complete, buf(it-1) reads done
        if (it < 30) {
            int bs_ = bV + 2; if (bs_ >= 3) bs_ -= 3;
            stage(bs_, it + 2);          // overwrite buf holding tile it-1
        }
        int bK = bV + 1; if (bK >= 3) bK -= 3;
        const _Float16* sKb = sK[bK];
        const _Float16* sVb = sV[bV];

        // S(it+1): 8 linear b128 reads + 32 MFMAs; all results stay live
        half8 kf[4][2];
#pragma unroll
        for (int mt = 0; mt < 4; ++mt)
#pragma unroll
            for (int ks = 0; ks < 2; ++ks)
                kf[mt][ks] = *(const half8*)&sKb[(mt * 2 + ks) * 512 + lb];

        f32x4 Sa[2][4], Sb[2][4];
#pragma unroll
        for (int sc2 = 0; sc2 < 2; ++sc2)
#pragma unroll
            for (int nt = 0; nt < 4; ++nt) {
                f32x4 t0 = __builtin_amdgcn_mfma_f32_16x16x32_f16(kf[2 * sc2][0], qb[nt][0], fz, 0, 0, 0);
                Sa[sc2][nt] = __builtin_amdgcn_mfma_f32_16x16x32_f16(kf[2 * sc2][1], qb[nt][1], t0, 0, 0, 0);
                f32x4 t1 = __builtin_amdgcn_mfma_f32_16x16x32_f16(kf[2 * sc2 + 1][0], qb[nt][0], fz, 0, 0, 0);
                Sb[sc2][nt] = __builtin_amdgcn_mfma_f32_16x16x32_f16(kf[2 * sc2 + 1][1], qb[nt][1], t1, 0, 0, 0);
            }

        // O(it) + Lacc on PFo, source-interleaved with exps(S(it+1)) -> PFn.
        // Group ct: 8 O-MFMA + 2 Lacc-MFMA  ||  16 exp + 8 pkrtz (independent).
#pragma unroll
        for (int ct = 0; ct < 4; ++ct) {
            half8 vf0 = *(const half8*)&sVb[(0 * 4 + ct) * 512 + lb];
            half8 vf1 = *(const half8*)&sVb[(1 * 4 + ct) * 512 + lb];
#pragma unroll
            for (int nt = 0; nt < 4; ++nt) {
                Oacc[ct][nt] = __builtin_amdgcn_mfma_f32_16x16x32_f16(
                    vf0, PFo[0][nt], Oacc[ct][nt], 0, 0, 0);
                Oacc[ct][nt] = __builtin_amdgcn_mfma_f32_16x16x32_f16(
                    vf1, PFo[1][nt], Oacc[ct][nt], 0, 0, 0);
            }
            Lacc[ct] = __builtin_amdgcn_mfma_f32_16x16x32_f16(ones, PFo[0][ct], Lacc[ct], 0, 0, 0);
            Lacc[ct] = __builtin_amdgcn_mfma_f32_16x16x32_f16(ones, PFo[1][ct], Lacc[ct], 0, 0, 0);

            {
                float e0 = fast_exp2(Sa[0][ct][0]);
                float e1 = fast_exp2(Sa[0][ct][1]);
                float e2 = fast_exp2(Sa[0][ct][2]);
                float e3 = fast_exp2(Sa[0][ct][3]);
                float e4 = fast_exp2(Sb[0][ct][0]);
                float e5 = fast_exp2(Sb[0][ct][1]);
                float e6 = fast_exp2(Sb[0][ct][2]);
                float e7 = fast_exp2(Sb[0][ct][3]);
                uint4 u = make_uint4(pkrtz(e0, e1), pkrtz(e2, e3),
                                     pkrtz(e4, e5), pkrtz(e6, e7));
                PFn[0][ct] = __builtin_bit_cast(half8, u);
            }
            {
                float e0 = fast_exp2(Sa[1][ct][0]);
                float e1 = fast_exp2(Sa[1][ct][1]);
                float e2 = fast_exp2(Sa[1][ct][2]);
                float e3 = fast_exp2(Sa[1][ct][3]);
                float e4 = fast_exp2(Sb[1][ct][0]);
                float e5 = fast_exp2(Sb[1][ct][1]);
                float e6 = fast_exp2(Sb[1][ct][2]);
                float e7 = fast_exp2(Sb[1][ct][3]);
                uint4 u = make_uint4(pkrtz(e0, e1), pkrtz(e2, e3),
                                     pkrtz(e4, e5), pkrtz(e6, e7));
                PFn[1][ct] = __builtin_bit_cast(half8, u);
            }
        }
        bV = bK;
    };

    // ---- prologue: prime pipeline with P(0) -> pfA (serial, once) ----
    __builtin_amdgcn_s_waitcnt(0);       // tiles 0 and 1 resident
    __syncthreads();
    {
        half8 kf[4][2];
#pragma unroll
        for (int mt = 0; mt < 4; ++mt)
#pragma unroll
            for (int ks = 0; ks < 2; ++ks)
                kf[mt][ks] = *(const half8*)&sK[0][(mt * 2 + ks) * 512 + lb];
#pragma unroll
        for (int sc2 = 0; sc2 < 2; ++sc2)
#pragma unroll
            for (int nt = 0; nt < 4; ++nt) {
                f32x4 t0 = __builtin_amdgcn_mfma_f32_16x16x32_f16(kf[2 * sc2][0], qb[nt][0], fz, 0, 0, 0);
                f32x4 Sa = __builtin_amdgcn_mfma_f32_16x16x32_f16(kf[2 * sc2][1], qb[nt][1], t0, 0, 0, 0);
                f32x4 t1 = __builtin_amdgcn_mfma_f32_16x16x32_f16(kf[2 * sc2 + 1][0], qb[nt][0], fz, 0, 0, 0);
                f32x4 Sb = __builtin_amdgcn_mfma_f32_16x16x32_f16(kf[2 * sc2 + 1][1], qb[nt][1], t1, 0, 0, 0);
                uint4 u = make_uint4(pkrtz(fast_exp2(Sa[0]), fast_exp2(Sa[1])),
                                     pkrtz(fast_exp2(Sa[2]), fast_exp2(Sa[3])),
                                     pkrtz(fast_exp2(Sb[0]), fast_exp2(Sb[1])),
                                     pkrtz(fast_exp2(Sb[2]), fast_exp2(Sb[3])));
                pfA[sc2][nt] = __builtin_bit_cast(half8, u);
            }
    }

    // ---- main loop: 31 body iterations, pf ping-pong, rolled pair loop ----
    for (int it = 0; it < 30; it += 2) {
        body(it,     pfA, pfB);
        body(it + 1, pfB, pfA);
    }
    body(30, pfA, pfB);

    // ---- peeled tail: O(31)+Lacc with pfB. sV[bV] staged at it=29, drained
    // at it=30's barrier; no LDS writes after -> no barrier needed here.
    {
        const _Float16* sVb = sV[bV];
#pragma unroll
        for (int ct = 0; ct < 4; ++ct) {
            half8 vf0 = *(const half8*)&sVb[(0 * 4 + ct) * 512 + lb];
            half8 vf1 = *(const half8*)&sVb[(1 * 4 + ct) * 512 + lb];
#pragma unroll
            for (int nt = 0; nt < 4; ++nt) {
                Oacc[ct][nt] = __builtin_amdgcn_mfma_f32_16x16x32_f16(
                    vf0, pfB[0][nt], Oacc[ct][nt], 0, 0, 0);
                Oacc[ct][nt] = __builtin_amdgcn_mfma_f32_16x16x32_f16(
                    vf1, pfB[1][nt], Oacc[ct][nt], 0, 0, 0);
            }
            Lacc[ct] = __builtin_amdgcn_mfma_f32_16x16x32_f16(ones, pfB[0][ct], Lacc[ct], 0, 0, 0);
            Lacc[ct] = __builtin_amdgcn_mfma_f32_16x16x32_f16(ones, pfB[1][ct], Lacc[ct], 0, 0, 0);
        }
    }

    // ---- epilogue: Lacc rows are identical (A=ones) -> no shuffles needed ----
    float inv[4];
#pragma unroll
    for (int nt = 0; nt < 4; ++nt) inv[nt] = 1.f / Lacc[nt][0];

    float* ob = out + (((size_t)(b4 * 1024 + h * 64)) << 11) + T0 + wave * 64;
#pragma unroll
    for (int ct = 0; ct < 4; ++ct)
#pragma unroll
        for (int nt = 0; nt < 4; ++nt) {
            f32x4 o = Oacc[ct][nt];
#pragma unroll
            for (int r = 0; r < 4; ++r)
                ob[((size_t)(ct * 16 + quad * 4 + r) << 11) + nt * 16 + l15] = o[r] * inv[nt];
        }
}

extern "C" void kernel_launch(void* const* d_in, const int* in_sizes, int n_in,
                              void* d_out, int out_size, void* d_ws, size_t ws_size,
                              hipStream_t stream) {
    const float* qkv = (const float*)d_in[0];
    float* out = (float*)d_out;
    _Float16* ws = (_Float16*)d_ws;
    prep_kernel<<<dim3(4096), dim3(256), 0, stream>>>(qkv, ws);
    attn_kernel<<<dim3(512), dim3(256), 0, stream>>>(qkv, ws, out);
}

// Round 3
// 215.660 us; speedup vs baseline: 1.0012x; 1.0012x over previous
//
#include <hip/hip_runtime.h>
#include <cstdint>

typedef _Float16 half8 __attribute__((ext_vector_type(8)));
typedef __fp16 fp16x2 __attribute__((ext_vector_type(2)));
typedef float f32x4 __attribute__((ext_vector_type(4)));

// ws layout (halfs), per head 2048*64 = 131072 per tensor:
//  Kt: [head] fragment-order: frag(st=s/16, ks) at (st*2+ks)*512 + lane*8,
//      lane(q,l15) 8 halfs = K[16st+l15][32ks+8q+j]           (A-frag for S^T)
//  Vt: [head] sigma-fragment-order: frag(sc=s/32, ct) at (sc*4+ct)*512 + lane*8,
//      lane(q,l15) 8 halfs j = V[16ct+l15][32sc+4q+(j&3)+16(j>>2)]  (A-frag for O)
#define HSTRIDE 131072
#define KOFF    ((size_t)64 * HSTRIDE)
#define VOFF    ((size_t)128 * HSTRIDE)

__device__ __forceinline__ float fast_exp2(float x) {
    return __builtin_amdgcn_exp2f(x);
}

__device__ __forceinline__ uint32_t pkrtz(float a, float b) {
    fp16x2 h = __builtin_amdgcn_cvt_pkrtz(a, b);
    return __builtin_bit_cast(uint32_t, h);
}

__device__ __forceinline__ void load_lds16(const _Float16* g, _Float16* l) {
    auto* g1 = reinterpret_cast<const __attribute__((address_space(1))) uint32_t*>(
        reinterpret_cast<uintptr_t>(g));
    auto* l3 = reinterpret_cast<__attribute__((address_space(3))) uint32_t*>(
        reinterpret_cast<uintptr_t>(l));
    __builtin_amdgcn_global_load_lds(g1, l3, 16, 0, 0);
}

// ---------------- prep: K transpose + V sigma-pack (unchanged) ----------------
__global__ __launch_bounds__(256) void prep_kernel(const float* __restrict__ qkv,
                                                   _Float16* __restrict__ ws)
{
    __shared__ float Lf[64 * 67];        // 16.75 KB (K branch only)

    const int tid  = threadIdx.x;
    const int lane = tid & 63;
    const int wave = tid >> 6;
    const int bid  = blockIdx.x;

    if (bid < 2048) {
        // ---- K ----
        const int head  = (bid >> 5) & 63;
        const int chunk = bid & 31;          // 64-wide s chunk
        const int b4 = head >> 4, h = head & 15;
        const float* src = qkv + (((size_t)(b4 * 3072 + h * 192 + 64)) << 11)
                         + chunk * 64;

#pragma unroll
        for (int k = 0; k < 4; ++k) {
            int idx = k * 256 + tid;
            int c = idx >> 4;
            int t4 = (idx & 15) << 2;
            float4 f = *(const float4*)&src[(((size_t)c) << 11) + t4];
            float* d = &Lf[c * 67 + t4];
            d[0] = f.x; d[1] = f.y; d[2] = f.z; d[3] = f.w;
        }
        __syncthreads();

        const int q = lane >> 4, l15 = lane & 15;
        const int scol = wave * 16 + l15;    // s within chunk
#pragma unroll
        for (int k = 0; k < 2; ++k) {
            uint32_t d[4];
#pragma unroll
            for (int j = 0; j < 4; ++j) {
                float a = Lf[(32 * k + 8 * q + 2 * j) * 67 + scol];
                float b = Lf[(32 * k + 8 * q + 2 * j + 1) * 67 + scol];
                d[j] = pkrtz(a, b);
            }
            size_t off = KOFF + (size_t)head * HSTRIDE
                       + (size_t)((((chunk * 4 + wave) * 2 + k) * 512) + lane * 8);
            *(uint4*)&ws[off] = make_uint4(d[0], d[1], d[2], d[3]);
        }
    } else {
        // ---- V ----
        const int vb = bid - 2048;
        const int head = vb >> 5, chunk = vb & 31;   // 64-s chunk
        const int b4 = head >> 4, h = head & 15;
        const float* src = qkv + (((size_t)(b4 * 3072 + h * 192 + 128)) << 11) + chunk * 64;
        const int q = lane >> 4, cl = lane & 15;
        const int c = wave * 16 + cl;
#pragma unroll
        for (int k = 0; k < 2; ++k) {
            const float* p = &src[((size_t)c << 11) + k * 32 + q * 4];
            float4 f0 = *(const float4*)&p[0];      // s = 4q..4q+3   (j=0..3)
            float4 f1 = *(const float4*)&p[16];     // s = 16+4q..+3  (j=4..7)
            size_t off = VOFF + (size_t)head * HSTRIDE
                       + (size_t)(((chunk * 2 + k) * 4 + wave) * 512 + lane * 8);
            *(uint4*)&ws[off] = make_uint4(pkrtz(f0.x, f0.y), pkrtz(f0.z, f0.w),
                                           pkrtz(f1.x, f1.y), pkrtz(f1.z, f1.w));
        }
    }
}

// ---------------- flash attention: SGB-pinned MFMA/TRANS/VALU interleave ----------------
// Round-11 change vs round-10: rounds 9/10 proved the limiter is phase
// serialization (MfmaUtil 42 + VALUBusy 39 SUM; each pipe's busy time equals
// its issued work, so neither stalls internally -- they just run back to
// back; the LLVM scheduler re-clusters any source-level interleave). Fix:
// T19 sched_group_barrier pins the emitted pipeline per iteration region:
//   8 MFMA head-start, then 32 x {2 MFMA, 2 TRANS(exp), 1 VALU(pkrtz)}
// totals = 72 MFMA / 64 TRANS / 32 VALU = exactly one iteration's stream.
// Deps make this legal: 4 S-MFMAs unlock 8 exps; O-MFMAs consume previous
// pf only. ds_read/VMEM/SALU left unpinned. Everything else identical to
// round-10 (clean A/B on the schedule pin).
__launch_bounds__(256, 2)
__global__ void attn_kernel(const float* __restrict__ qkv,
                            const _Float16* __restrict__ ws, float* __restrict__ out)
{
    __shared__ __align__(16) _Float16 sK[3][4096];   // 3 x 8 KB, fragment-linear
    __shared__ __align__(16) _Float16 sV[3][4096];   // 3 x 8 KB, fragment-linear

    const int tid  = threadIdx.x;
    const int lane = tid & 63;
    const int wave = tid >> 6;
    const int l15  = lane & 15;
    const int quad = lane >> 4;

    const int bid  = blockIdx.x;
    const int head = bid & 63;
    const int tblk = bid >> 6;
    const int T0   = tblk * 256;
    const int b4   = head >> 4;
    const int h    = head & 15;

    const _Float16* Kt = ws + KOFF + (size_t)head * HSTRIDE;
    const _Float16* Vt = ws + VOFF + (size_t)head * HSTRIDE;
    const float*    Qg = qkv + ((size_t)(b4 * 3072 + h * 192) << 11);
    const float kQ = 0.125f * 1.44269504088896340736f;  // scale^2 * log2(e)

    f32x4 Oacc[4][4];
#pragma unroll
    for (int ct = 0; ct < 4; ++ct)
#pragma unroll
        for (int nt = 0; nt < 4; ++nt) Oacc[ct][nt] = (f32x4)0.f;
    f32x4 Lacc[4];
#pragma unroll
    for (int nt = 0; nt < 4; ++nt) Lacc[nt] = (f32x4)0.f;
    const f32x4 fz = (f32x4)0.f;

    half8 ones;
#pragma unroll
    for (int j = 0; j < 8; ++j) ones[j] = (_Float16)1.0f;

    const int lb = lane * 8;

    auto stage = [&](int buf, int tile) {
        const _Float16* kg = Kt + (size_t)tile * 4096 + wave * 1024 + lane * 8;
        const _Float16* vg = Vt + (size_t)tile * 4096 + wave * 1024 + lane * 8;
        load_lds16(kg,       &sK[buf][wave * 1024]);
        load_lds16(kg + 512, &sK[buf][wave * 1024 + 512]);
        load_lds16(vg,       &sV[buf][wave * 1024]);
        load_lds16(vg + 512, &sV[buf][wave * 1024 + 512]);
    };

    stage(0, 0);   // tiles 0 and 1 in flight before/under the Q gather
    stage(1, 1);

    // Q B-frags: B[k=c=32ks+8q+j][n=t=16nt+l15], direct fp32 gather + scale + pack.
    half8 qb[4][2];
#pragma unroll
    for (int nt = 0; nt < 4; ++nt) {
        const int t = T0 + wave * 64 + nt * 16 + l15;
#pragma unroll
        for (int ks = 0; ks < 2; ++ks) {
            float f[8];
#pragma unroll
            for (int j = 0; j < 8; ++j)
                f[j] = Qg[((size_t)(ks * 32 + quad * 8 + j) << 11) + t];
            uint4 u = make_uint4(pkrtz(f[0] * kQ, f[1] * kQ), pkrtz(f[2] * kQ, f[3] * kQ),
                                 pkrtz(f[4] * kQ, f[5] * kQ), pkrtz(f[6] * kQ, f[7] * kQ));
            qb[nt][ks] = __builtin_bit_cast(half8, u);
        }
    }

    half8 pfA[2][4], pfB[2][4];   // P^T B-frags, ping-pong pipeline state
    int bV = 0;                   // buffer holding tile `it` (tile t -> buf t%3)

    // ---- loop body: O(it) with PFo, S(it+1) -> exps -> PFn ----
    auto body = [&](int it, half8 (&PFo)[2][4], half8 (&PFn)[2][4]) {
        __builtin_amdgcn_s_waitcnt(0);   // own prefetch (tile it+1) resident
        __syncthreads();                 // all waves: tile it+1 complete, buf(it-1) reads done
        if (it < 30) {
            int bs_ = bV + 2; if (bs_ >= 3) bs_ -= 3;
            stage(bs_, it + 2);          // overwrite buf holding tile it-1
        }
        int bK = bV + 1; if (bK >= 3) bK -= 3;
        const _Float16* sKb = sK[bK];
        const _Float16* sVb = sV[bV];

        // S(it+1): 8 linear b128 reads + 32 MFMAs; all results stay live
        half8 kf[4][2];
#pragma unroll
        for (int mt = 0; mt < 4; ++mt)
#pragma unroll
            for (int ks = 0; ks < 2; ++ks)
                kf[mt][ks] = *(const half8*)&sKb[(mt * 2 + ks) * 512 + lb];

        f32x4 Sa[2][4], Sb[2][4];
#pragma unroll
        for (int sc2 = 0; sc2 < 2; ++sc2)
#pragma unroll
            for (int nt = 0; nt < 4; ++nt) {
                f32x4 t0 = __builtin_amdgcn_mfma_f32_16x16x32_f16(kf[2 * sc2][0], qb[nt][0], fz, 0, 0, 0);
                Sa[sc2][nt] = __builtin_amdgcn_mfma_f32_16x16x32_f16(kf[2 * sc2][1], qb[nt][1], t0, 0, 0, 0);
                f32x4 t1 = __builtin_amdgcn_mfma_f32_16x16x32_f16(kf[2 * sc2 + 1][0], qb[nt][0], fz, 0, 0, 0);
                Sb[sc2][nt] = __builtin_amdgcn_mfma_f32_16x16x32_f16(kf[2 * sc2 + 1][1], qb[nt][1], t1, 0, 0, 0);
            }

        // O(it) + Lacc on PFo, with exps(S(it+1)) -> PFn. Emitted order is
        // governed by the SGB pipeline below, not by source order.
#pragma unroll
        for (int ct = 0; ct < 4; ++ct) {
            half8 vf0 = *(const half8*)&sVb[(0 * 4 + ct) * 512 + lb];
            half8 vf1 = *(const half8*)&sVb[(1 * 4 + ct) * 512 + lb];
#pragma unroll
            for (int nt = 0; nt < 4; ++nt) {
                Oacc[ct][nt] = __builtin_amdgcn_mfma_f32_16x16x32_f16(
                    vf0, PFo[0][nt], Oacc[ct][nt], 0, 0, 0);
                Oacc[ct][nt] = __builtin_amdgcn_mfma_f32_16x16x32_f16(
                    vf1, PFo[1][nt], Oacc[ct][nt], 0, 0, 0);
            }
            Lacc[ct] = __builtin_amdgcn_mfma_f32_16x16x32_f16(ones, PFo[0][ct], Lacc[ct], 0, 0, 0);
            Lacc[ct] = __builtin_amdgcn_mfma_f32_16x16x32_f16(ones, PFo[1][ct], Lacc[ct], 0, 0, 0);

            {
                float e0 = fast_exp2(Sa[0][ct][0]);
                float e1 = fast_exp2(Sa[0][ct][1]);
                float e2 = fast_exp2(Sa[0][ct][2]);
                float e3 = fast_exp2(Sa[0][ct][3]);
                float e4 = fast_exp2(Sb[0][ct][0]);
                float e5 = fast_exp2(Sb[0][ct][1]);
                float e6 = fast_exp2(Sb[0][ct][2]);
                float e7 = fast_exp2(Sb[0][ct][3]);
                uint4 u = make_uint4(pkrtz(e0, e1), pkrtz(e2, e3),
                                     pkrtz(e4, e5), pkrtz(e6, e7));
                PFn[0][ct] = __builtin_bit_cast(half8, u);
            }
            {
                float e0 = fast_exp2(Sa[1][ct][0]);
                float e1 = fast_exp2(Sa[1][ct][1]);
                float e2 = fast_exp2(Sa[1][ct][2]);
                float e3 = fast_exp2(Sa[1][ct][3]);
                float e4 = fast_exp2(Sb[1][ct][0]);
                float e5 = fast_exp2(Sb[1][ct][1]);
                float e6 = fast_exp2(Sb[1][ct][2]);
                float e7 = fast_exp2(Sb[1][ct][3]);
                uint4 u = make_uint4(pkrtz(e0, e1), pkrtz(e2, e3),
                                     pkrtz(e4, e5), pkrtz(e6, e7));
                PFn[1][ct] = __builtin_bit_cast(half8, u);
            }
        }

        // ---- T19 pipeline pin for this barrier-to-barrier region ----
        // masks: MFMA=0x8, VALU=0x2 (excl. TRANS on this LLVM), TRANS=0x400.
        // 8 MFMA head start (S sc2=0 lead), then 32 x {2 MFMA, 2 TRANS, 1 VALU}
        // = 72 MFMA, 64 TRANS(exp), 32 VALU(pkrtz). Deps self-select: only
        // ready exps (whose S-MFMA retired) can fill early TRANS slots.
        __builtin_amdgcn_sched_group_barrier(0x008, 8, 0);
#pragma unroll
        for (int g = 0; g < 32; ++g) {
            __builtin_amdgcn_sched_group_barrier(0x008, 2, 0);
            __builtin_amdgcn_sched_group_barrier(0x400, 2, 0);
            __builtin_amdgcn_sched_group_barrier(0x002, 1, 0);
        }
        bV = bK;
    };

    // ---- prologue: prime pipeline with P(0) -> pfA (serial, once) ----
    __builtin_amdgcn_s_waitcnt(0);       // tiles 0 and 1 resident
    __syncthreads();
    {
        half8 kf[4][2];
#pragma unroll
        for (int mt = 0; mt < 4; ++mt)
#pragma unroll
            for (int ks = 0; ks < 2; ++ks)
                kf[mt][ks] = *(const half8*)&sK[0][(mt * 2 + ks) * 512 + lb];
#pragma unroll
        for (int sc2 = 0; sc2 < 2; ++sc2)
#pragma unroll
            for (int nt = 0; nt < 4; ++nt) {
                f32x4 t0 = __builtin_amdgcn_mfma_f32_16x16x32_f16(kf[2 * sc2][0], qb[nt][0], fz, 0, 0, 0);
                f32x4 Sa = __builtin_amdgcn_mfma_f32_16x16x32_f16(kf[2 * sc2][1], qb[nt][1], t0, 0, 0, 0);
                f32x4 t1 = __builtin_amdgcn_mfma_f32_16x16x32_f16(kf[2 * sc2 + 1][0], qb[nt][0], fz, 0, 0, 0);
                f32x4 Sb = __builtin_amdgcn_mfma_f32_16x16x32_f16(kf[2 * sc2 + 1][1], qb[nt][1], t1, 0, 0, 0);
                uint4 u = make_uint4(pkrtz(fast_exp2(Sa[0]), fast_exp2(Sa[1])),
                                     pkrtz(fast_exp2(Sa[2]), fast_exp2(Sa[3])),
                                     pkrtz(fast_exp2(Sb[0]), fast_exp2(Sb[1])),
                                     pkrtz(fast_exp2(Sb[2]), fast_exp2(Sb[3])));
                pfA[sc2][nt] = __builtin_bit_cast(half8, u);
            }
    }

    // ---- main loop: 31 body iterations, pf ping-pong, rolled pair loop ----
    for (int it = 0; it < 30; it += 2) {
        body(it,     pfA, pfB);
        body(it + 1, pfB, pfA);
    }
    body(30, pfA, pfB);

    // ---- peeled tail: O(31)+Lacc with pfB. sV[bV] staged at it=29, drained
    // at it=30's barrier; no LDS writes after -> no barrier needed here.
    {
        const _Float16* sVb = sV[bV];
#pragma unroll
        for (int ct = 0; ct < 4; ++ct) {
            half8 vf0 = *(const half8*)&sVb[(0 * 4 + ct) * 512 + lb];
            half8 vf1 = *(const half8*)&sVb[(1 * 4 + ct) * 512 + lb];
#pragma unroll
            for (int nt = 0; nt < 4; ++nt) {
                Oacc[ct][nt] = __builtin_amdgcn_mfma_f32_16x16x32_f16(
                    vf0, pfB[0][nt], Oacc[ct][nt], 0, 0, 0);
                Oacc[ct][nt] = __builtin_amdgcn_mfma_f32_16x16x32_f16(
                    vf1, pfB[1][nt], Oacc[ct][nt], 0, 0, 0);
            }
            Lacc[ct] = __builtin_amdgcn_mfma_f32_16x16x32_f16(ones, pfB[0][ct], Lacc[ct], 0, 0, 0);
            Lacc[ct] = __builtin_amdgcn_mfma_f32_16x16x32_f16(ones, pfB[1][ct], Lacc[ct], 0, 0, 0);
        }
    }

    // ---- epilogue: Lacc rows are identical (A=ones) -> no shuffles needed ----
    float inv[4];
#pragma unroll
    for (int nt = 0; nt < 4; ++nt) inv[nt] = 1.f / Lacc[nt][0];

    float* ob = out + (((size_t)(b4 * 1024 + h * 64)) << 11) + T0 + wave * 64;
#pragma unroll
    for (int ct = 0; ct < 4; ++ct)
#pragma unroll
        for (int nt = 0; nt < 4; ++nt) {
            f32x4 o = Oacc[ct][nt];
#pragma unroll
            for (int r = 0; r < 4; ++r)
                ob[((size_t)(ct * 16 + quad * 4 + r) << 11) + nt * 16 + l15] = o[r] * inv[nt];
        }
}

extern "C" void kernel_launch(void* const* d_in, const int* in_sizes, int n_in,
                              void* d_out, int out_size, void* d_ws, size_t ws_size,
                              hipStream_t stream) {
    const float* qkv = (const float*)d_in[0];
    float* out = (float*)d_out;
    _Float16* ws = (_Float16*)d_ws;
    prep_kernel<<<dim3(4096), dim3(256), 0, stream>>>(qkv, ws);
    attn_kernel<<<dim3(512), dim3(256), 0, stream>>>(qkv, ws, out);
}